// Round 17
// baseline (171.481 us; speedup 1.0000x reference)
//
#include <hip/hip_runtime.h>
#include <math.h>

#define BATCH 4
#define TLEN 512
#define SLEN 512
#define DM 256
#define NH 4
#define DH 64
#define BT (BATCH * TLEN)   // 2048

typedef float f2 __attribute__((ext_vector_type(2)));

__device__ __forceinline__ float rcp_fast(float x) { return __builtin_amdgcn_rcpf(x); }
__device__ __forceinline__ f2 f2fma(f2 a, f2 b, f2 c) { return __builtin_elementwise_fma(a, b, c); }
__device__ __forceinline__ f2 s2(float v) { f2 r; r.x = v; r.y = v; return r; }

// ---- 64x64 tile transpose of a DMxDM matrix; y selects one of 4 matrices ----
__global__ __launch_bounds__(256) void transposeN_kernel(
    const float* __restrict__ s0, const float* __restrict__ s1,
    const float* __restrict__ s2_, const float* __restrict__ s3,
    float* __restrict__ d0, float* __restrict__ d1,
    float* __restrict__ d2, float* __restrict__ d3) {
  __shared__ float tile[64][65];
  int m = blockIdx.y;
  const float* S = (m == 0) ? s0 : (m == 1) ? s1 : (m == 2) ? s2_ : s3;
  float* D = (m == 0) ? d0 : (m == 1) ? d1 : (m == 2) ? d2 : d3;
  int bx = blockIdx.x;
  int to = (bx & 3) * 64;
  int tk = (bx >> 2) * 64;
  int lo = threadIdx.x >> 6;
  int lk = threadIdx.x & 63;
#pragma unroll
  for (int p = 0; p < 16; ++p) {
    int o = p * 4 + lo;
    tile[o][lk] = S[(size_t)(to + o) * DM + tk + lk];
  }
  __syncthreads();
#pragma unroll
  for (int p = 0; p < 16; ++p) {
    int kk = p * 4 + lo;
    D[(size_t)(tk + kk) * DM + to + lk] = tile[lk][kk];
  }
}

// ---- kernel A: block = 16 rows x 64 outs; lane = out col; W traffic 64KB/block.
//      EQ=[bh][t][d]; EKT=[bh][dc16][q4][lane64][d4][2] (s-pair interleaved);
//      Vw=[bh][s/2][d][2] ----
__global__ __launch_bounds__(256) void proj_kernel(
    const float* __restrict__ q, const float* __restrict__ k, const float* __restrict__ v,
    const float* __restrict__ wqt, const float* __restrict__ wkt, const float* __restrict__ wvt,
    float* __restrict__ EQ, float* __restrict__ EKT, float* __restrict__ Vw) {
  int tid = threadIdx.x;
  int lane = tid & 63;
  int wid = __builtin_amdgcn_readfirstlane(tid >> 6);
  int which = blockIdx.y;
  const float* X = (which == 0) ? q : (which == 1) ? k : v;
  const float* WT = (which == 0) ? wqt : (which == 1) ? wkt : wvt;
  int row0 = (blockIdx.x >> 2) * 16 + wid * 4;     // 128 row-tiles of 16
  int o = (blockIdx.x & 3) * 64 + lane;            // 4 out-slices of 64
  const float* xb = X + (size_t)row0 * DM;         // wave-uniform -> s_load
  const float* wcol = WT + o;                      // [k][o]: b32 coalesced 256B/instr
  float a0 = 0.f, a1 = 0.f, a2 = 0.f, a3 = 0.f;
#pragma unroll 8
  for (int kk = 0; kk < DM; ++kk) {
    float w = wcol[(size_t)kk * DM];
    a0 = fmaf(xb[kk], w, a0);
    a1 = fmaf(xb[DM + kk], w, a1);
    a2 = fmaf(xb[2 * DM + kk], w, a2);
    a3 = fmaf(xb[3 * DM + kk], w, a3);
  }
  int h = o >> 6, d = o & 63;
  float accs[4] = {a0, a1, a2, a3};
#pragma unroll
  for (int r = 0; r < 4; ++r) {
    int row = row0 + r;
    int b = row >> 9, t = row & 511;
    int bh = b * NH + h;
    float val = accs[r];
    if (which < 2) {
      // clamp +-5.5 (6.9 sigma; P(hit)~3e-6): quad product A0..A3 <= e^88 < fp32 max
      val = __expf(2.f * fminf(fmaxf(val, -5.5f), 5.5f));
    }
    if (which == 0) {
      EQ[((size_t)bh * TLEN + t) * DH + d] = val;
    } else if (which == 1) {
      int dc = d >> 2, j = d & 3, qq = t >> 7, l = t & 63, hi = (t >> 6) & 1;
      EKT[((((size_t)bh * 16 + dc) * 4 + qq) * 64 + l) * 8 + j * 2 + hi] = val;
    } else {
      Vw[(size_t)bh * SLEN * DH + (size_t)(t >> 1) * 128 + d * 2 + (t & 1)] = val;
    }
  }
}

// ---- kernel B: R16 structure + 3-buffer EK rotation (2-dc lookahead).
//      block = (bh, 4 t-rows); wave owns s-quarter; packed f32x2 score loop. ----
__global__ __launch_bounds__(256, 8) void attn_kernel(
    const float* __restrict__ EQ, const float* __restrict__ EKT,
    const float* __restrict__ Vw, const float* __restrict__ va_g,
    float* __restrict__ attn_out, float* __restrict__ attended) {
  __shared__ float pw[4][SLEN];      // probs, t-major
  __shared__ float fp[4][4][64];     // per-wave PV partials
  __shared__ float sred[4][4];       // cross-wave softmax sums
  int tid = threadIdx.x;
  int lane = tid & 63;
  int wid = __builtin_amdgcn_readfirstlane(tid >> 6);
  int bx = (int)((blockIdx.x & 7) * 256 + (blockIdx.x >> 3));  // bijective XCD swizzle (2048=8*256)
  int bh = bx >> 7;
  int tile = (bx & 127) * 4;
  int h = bh & 3, b = bh >> 2;
  int sq0 = wid * 128;               // this wave's s-quarter base

  // EKT[bh][dc][q=wid][lane][8]: per lane 32B = {d0_lo,d0_hi,...,d3_lo,d3_hi}
  const float* ekb = EKT + (size_t)bh * (16 * 2048) + wid * 512 + lane * 8;
  const float* eqb = EQ + ((size_t)bh * TLEN + tile) * DH;   // uniform -> s_load
  const float* vap = va_g + h * DH;

  f2 acc2[4];
#pragma unroll
  for (int t = 0; t < 4; ++t) acc2[t] = s2(0.f);
  float vsum = 0.f;

  f2 eA0, eA1, eA2, eA3, eB0, eB1, eB2, eB3, eC0, eC1, eC2, eC3;

#define LOADP(S, dc_) do {                                                  \
    const f2* _p = (const f2*)(ekb + (size_t)(dc_) * 2048);                 \
    e##S##0 = _p[0]; e##S##1 = _p[1]; e##S##2 = _p[2]; e##S##3 = _p[3];     \
  } while (0)

  // packed quad-combined rcp: both s-slots in one f2 stream; 14 pk-VALU + 2 rcp
#define SC4P(E0, E1, E2, E3, qv, av, aref) do {                             \
    f2 A0 = f2fma(s2(qv.x), E0, s2(1.f));                                   \
    f2 A1 = f2fma(s2(qv.y), E1, s2(1.f));                                   \
    f2 A2 = f2fma(s2(qv.z), E2, s2(1.f));                                   \
    f2 A3 = f2fma(s2(qv.w), E3, s2(1.f));                                   \
    f2 n01 = f2fma(s2(av.x), A1, s2(av.y) * A0);                            \
    f2 n23 = f2fma(s2(av.z), A3, s2(av.w) * A2);                            \
    f2 P01 = A0 * A1, P23 = A2 * A3;                                        \
    f2 Nm = f2fma(n01, P23, n23 * P01);                                     \
    f2 PP = P01 * P23;                                                      \
    f2 R; R.x = rcp_fast(PP.x); R.y = rcp_fast(PP.y);                       \
    aref = f2fma(Nm, R, aref);                                              \
  } while (0)

  // compute buffer C_ (= dc%3); prefetch dc+2 into L_ (= (dc+2)%3)
#define DCB(C_, L_, dc_) do {                                               \
    float4 av = *(const float4*)(vap + (dc_) * 4);                          \
    float4 q0 = *(const float4*)(eqb + 0 * DH + (dc_) * 4);                 \
    float4 q1 = *(const float4*)(eqb + 1 * DH + (dc_) * 4);                 \
    float4 q2 = *(const float4*)(eqb + 2 * DH + (dc_) * 4);                 \
    float4 q3 = *(const float4*)(eqb + 3 * DH + (dc_) * 4);                 \
    vsum += (av.x + av.y) + (av.z + av.w);                                  \
    if ((dc_) < 14) LOADP(L_, (dc_) + 2);                                   \
    __builtin_amdgcn_sched_barrier(0);                                      \
    SC4P(e##C_##0, e##C_##1, e##C_##2, e##C_##3, q0, av, acc2[0]);          \
    SC4P(e##C_##0, e##C_##1, e##C_##2, e##C_##3, q1, av, acc2[1]);          \
    SC4P(e##C_##0, e##C_##1, e##C_##2, e##C_##3, q2, av, acc2[2]);          \
    SC4P(e##C_##0, e##C_##1, e##C_##2, e##C_##3, q3, av, acc2[3]);          \
  } while (0)

  LOADP(A, 0);
  LOADP(B, 1);
  DCB(A, C, 0);  DCB(B, A, 1);  DCB(C, B, 2);
  DCB(A, C, 3);  DCB(B, A, 4);  DCB(C, B, 5);
  DCB(A, C, 6);  DCB(B, A, 7);  DCB(C, B, 8);
  DCB(A, C, 9);  DCB(B, A, 10); DCB(C, B, 11);
  DCB(A, C, 12); DCB(B, A, 13); DCB(C, B, 14);
  DCB(A, C, 15);

  // ---- softmax, no max-subtraction (|score| <= 0.125*sum|va| ~ 7, exp bounded) ----
  size_t bht = (size_t)bh * TLEN + tile;
  float e0[4], e1[4];
#pragma unroll
  for (int t = 0; t < 4; ++t) {
    float x0 = __expf(fmaf(acc2[t].x, -0.25f, vsum * 0.125f));
    float x1 = __expf(fmaf(acc2[t].y, -0.25f, vsum * 0.125f));
    e0[t] = x0; e1[t] = x1;
    float es = x0 + x1;
#pragma unroll
    for (int off = 32; off; off >>= 1) es += __shfl_xor(es, off);
    if (lane == 0) sred[t][wid] = es;
  }
  __syncthreads();
#pragma unroll
  for (int t = 0; t < 4; ++t) {
    float es = (sred[t][0] + sred[t][1]) + (sred[t][2] + sred[t][3]);
    float inv = rcp_fast(es);
    float p0 = e0[t] * inv, p1 = e1[t] * inv;
    pw[t][sq0 + lane] = p0;                 // own-wave region: no barrier needed
    pw[t][sq0 + 64 + lane] = p1;
    float* arow = attn_out + (bht + t) * SLEN + sq0;
    arow[lane] = p0;                        // coalesced 256B stores
    arow[64 + lane] = p1;
  }

  // ---- PV over own s-quarter: lane = d; probs via LDS broadcast (own writes) ----
  const float2* vb = (const float2*)Vw + (size_t)bh * (256 * 64) + (size_t)(wid * 64) * 64 + lane;
  float f[4];
#pragma unroll
  for (int t = 0; t < 4; ++t) f[t] = 0.f;
#pragma unroll 2
  for (int i = 0; i < 32; ++i) {            // s-quads within quarter
    float2 v01 = vb[(size_t)i * 128];       // coalesced b64: s-pair, d=lane
    float2 v23 = vb[(size_t)i * 128 + 64];
    int sb = sq0 + i * 4;
#pragma unroll
    for (int t = 0; t < 4; ++t) {
      float4 pq = *(const float4*)&pw[t][sb];   // uniform addr -> LDS broadcast
      f[t] = fmaf(pq.x, v01.x, f[t]);
      f[t] = fmaf(pq.y, v01.y, f[t]);
      f[t] = fmaf(pq.z, v23.x, f[t]);
      f[t] = fmaf(pq.w, v23.y, f[t]);
    }
  }
#pragma unroll
  for (int t = 0; t < 4; ++t) fp[wid][t][lane] = f[t];
  __syncthreads();
  {
    int t = wid;                            // wave reduces 1 t-row
    float s = (fp[0][t][lane] + fp[1][t][lane]) + (fp[2][t][lane] + fp[3][t][lane]);
    attended[((size_t)(b * TLEN) + tile + t) * DM + h * DH + lane] = s;
  }
}

// ---- kernel C: out = attended @ w_o.T; block = 8 rows x 64 outs, grid 1024 ----
__global__ __launch_bounds__(256) void outproj_kernel(
    const float* __restrict__ att, const float* __restrict__ wot,
    float* __restrict__ out) {
  int tid = threadIdx.x;
  int lane = tid & 63;
  int wid = __builtin_amdgcn_readfirstlane(tid >> 6);
  int row0 = (blockIdx.x >> 2) * 8 + wid * 2;
  int o = (blockIdx.x & 3) * 64 + lane;
  const float* xb = att + (size_t)row0 * DM;       // wave-uniform -> s_load
  const float* wcol = wot + o;
  float a0 = 0.f, a1 = 0.f;
#pragma unroll 8
  for (int kk = 0; kk < DM; ++kk) {
    float w = wcol[(size_t)kk * DM];
    a0 = fmaf(xb[kk], w, a0);
    a1 = fmaf(xb[DM + kk], w, a1);
  }
  out[(size_t)(row0 + 0) * DM + o] = a0;
  out[(size_t)(row0 + 1) * DM + o] = a1;
}

extern "C" void kernel_launch(void* const* d_in, const int* in_sizes, int n_in,
                              void* d_out, int out_size, void* d_ws, size_t ws_size,
                              hipStream_t stream) {
  const float* query = (const float*)d_in[0];
  const float* key   = (const float*)d_in[1];
  const float* value = (const float*)d_in[2];
  const float* wq    = (const float*)d_in[3];
  const float* wk    = (const float*)d_in[4];
  const float* wv    = (const float*)d_in[5];
  const float* va    = (const float*)d_in[6];
  const float* wo    = (const float*)d_in[7];

  float* out  = (float*)d_out;                 // (B,T,DM)
  float* attn = out + (size_t)BT * DM;         // (B,H,T,S)

  const size_t SEG = (size_t)BT * DM;          // 524288 floats = 2MB
  float* EQ  = (float*)d_ws;                   // [bh][t][d]
  float* EKT = EQ + SEG;                       // [bh][dc16][q4][lane64][d4][2]
  float* Vw  = EKT + SEG;                      // [bh][s/2][d][2]
  float* att = Vw + SEG;                       // attended [b][t][h*64+d]

  bool big_ws = ws_size >= (4 * SEG + 4 * (size_t)DM * DM) * sizeof(float);

  if (big_ws) {
    // weights live past 8MB: all 4 transposes front-loaded, 4 kernels total
    float* WTq = att + SEG;
    float* WTk = WTq + (size_t)DM * DM;
    float* WTv = WTk + (size_t)DM * DM;
    float* WoT = WTv + (size_t)DM * DM;
    transposeN_kernel<<<dim3(16, 4), 256, 0, stream>>>(wq, wk, wv, wo, WTq, WTk, WTv, WoT);
    proj_kernel<<<dim3(512, 3), 256, 0, stream>>>(query, key, value, WTq, WTk, WTv, EQ, EKT, Vw);
    attn_kernel<<<dim3(2048), 256, 0, stream>>>(EQ, EKT, Vw, va, attn, att);
    outproj_kernel<<<dim3(1024), 256, 0, stream>>>(att, WoT, out);
  } else {
    // fallback: overlay weights in dead regions (5 kernels)
    float* WTq = att;                          // dead until attn writes att
    float* WTk = att + (size_t)DM * DM;
    float* WTv = att + 2 * (size_t)DM * DM;
    float* WoT = EQ;                           // EQ dead after attn
    transposeN_kernel<<<dim3(16, 3), 256, 0, stream>>>(wq, wk, wv, wv, WTq, WTk, WTv, WTv);
    proj_kernel<<<dim3(512, 3), 256, 0, stream>>>(query, key, value, WTq, WTk, WTv, EQ, EKT, Vw);
    attn_kernel<<<dim3(2048), 256, 0, stream>>>(EQ, EKT, Vw, va, attn, att);
    transposeN_kernel<<<dim3(16, 1), 256, 0, stream>>>(wo, wo, wo, wo, WoT, WoT, WoT, WoT);
    outproj_kernel<<<dim3(1024), 256, 0, stream>>>(att, WoT, out);
  }
}

// Round 18
// 86.758 us; speedup vs baseline: 1.9766x; 1.9766x over previous
//
#include <hip/hip_runtime.h>
#include <math.h>

#define BATCH 4
#define TLEN 512
#define SLEN 512
#define DM 256
#define NH 4
#define DH 64
#define BT (BATCH * TLEN)   // 2048

typedef float f2 __attribute__((ext_vector_type(2)));

__device__ __forceinline__ float rcp_fast(float x) { return __builtin_amdgcn_rcpf(x); }
__device__ __forceinline__ f2 f2fma(f2 a, f2 b, f2 c) { return __builtin_elementwise_fma(a, b, c); }
__device__ __forceinline__ f2 s2(float v) { f2 r; r.x = v; r.y = v; return r; }

// ---- 64x64 tile transpose of a DMxDM matrix; y selects one of 4 matrices ----
__global__ __launch_bounds__(256) void transposeN_kernel(
    const float* __restrict__ s0, const float* __restrict__ s1,
    const float* __restrict__ s2_, const float* __restrict__ s3,
    float* __restrict__ d0, float* __restrict__ d1,
    float* __restrict__ d2, float* __restrict__ d3) {
  __shared__ float tile[64][65];
  int m = blockIdx.y;
  const float* S = (m == 0) ? s0 : (m == 1) ? s1 : (m == 2) ? s2_ : s3;
  float* D = (m == 0) ? d0 : (m == 1) ? d1 : (m == 2) ? d2 : d3;
  int bx = blockIdx.x;
  int to = (bx & 3) * 64;
  int tk = (bx >> 2) * 64;
  int lo = threadIdx.x >> 6;
  int lk = threadIdx.x & 63;
#pragma unroll
  for (int p = 0; p < 16; ++p) {
    int o = p * 4 + lo;
    tile[o][lk] = S[(size_t)(to + o) * DM + tk + lk];
  }
  __syncthreads();
#pragma unroll
  for (int p = 0; p < 16; ++p) {
    int kk = p * 4 + lo;
    D[(size_t)(tk + kk) * DM + to + lk] = tile[lk][kk];
  }
}

// ---- kernel A: block = 16 rows x 64 outs; lane = out col; W traffic 64KB/block.
//      EQ=[bh][t][d]; EKT=[bh][dc16][q4][lane64][d4][2] (s-pair interleaved);
//      Vw=[bh][s/2][d][2] ----
__global__ __launch_bounds__(256) void proj_kernel(
    const float* __restrict__ q, const float* __restrict__ k, const float* __restrict__ v,
    const float* __restrict__ wqt, const float* __restrict__ wkt, const float* __restrict__ wvt,
    float* __restrict__ EQ, float* __restrict__ EKT, float* __restrict__ Vw) {
  int tid = threadIdx.x;
  int lane = tid & 63;
  int wid = __builtin_amdgcn_readfirstlane(tid >> 6);
  int which = blockIdx.y;
  const float* X = (which == 0) ? q : (which == 1) ? k : v;
  const float* WT = (which == 0) ? wqt : (which == 1) ? wkt : wvt;
  int row0 = (blockIdx.x >> 2) * 16 + wid * 4;     // 128 row-tiles of 16
  int o = (blockIdx.x & 3) * 64 + lane;            // 4 out-slices of 64
  const float* xb = X + (size_t)row0 * DM;         // wave-uniform -> s_load
  const float* wcol = WT + o;                      // [k][o]: b32 coalesced 256B/instr
  float a0 = 0.f, a1 = 0.f, a2 = 0.f, a3 = 0.f;
#pragma unroll 8
  for (int kk = 0; kk < DM; ++kk) {
    float w = wcol[(size_t)kk * DM];
    a0 = fmaf(xb[kk], w, a0);
    a1 = fmaf(xb[DM + kk], w, a1);
    a2 = fmaf(xb[2 * DM + kk], w, a2);
    a3 = fmaf(xb[3 * DM + kk], w, a3);
  }
  int h = o >> 6, d = o & 63;
  float accs[4] = {a0, a1, a2, a3};
#pragma unroll
  for (int r = 0; r < 4; ++r) {
    int row = row0 + r;
    int b = row >> 9, t = row & 511;
    int bh = b * NH + h;
    float val = accs[r];
    if (which < 2) {
      // clamp +-5.5 (6.9 sigma; P(hit)~3e-6): quad product A0..A3 <= e^88 < fp32 max
      val = __expf(2.f * fminf(fmaxf(val, -5.5f), 5.5f));
    }
    if (which == 0) {
      EQ[((size_t)bh * TLEN + t) * DH + d] = val;
    } else if (which == 1) {
      int dc = d >> 2, j = d & 3, qq = t >> 7, l = t & 63, hi = (t >> 6) & 1;
      EKT[((((size_t)bh * 16 + dc) * 4 + qq) * 64 + l) * 8 + j * 2 + hi] = val;
    } else {
      Vw[(size_t)bh * SLEN * DH + (size_t)(t >> 1) * 128 + d * 2 + (t & 1)] = val;
    }
  }
}

// ---- kernel B: block = (bh, 4 t-rows); wave owns s-quarter; packed f32x2 score loop ----
__global__ __launch_bounds__(256, 8) void attn_kernel(
    const float* __restrict__ EQ, const float* __restrict__ EKT,
    const float* __restrict__ Vw, const float* __restrict__ va_g,
    float* __restrict__ attn_out, float* __restrict__ attended) {
  __shared__ float pw[4][SLEN];      // probs, t-major
  __shared__ float fp[4][4][64];     // per-wave PV partials
  __shared__ float sred[4][4];       // cross-wave softmax sums
  int tid = threadIdx.x;
  int lane = tid & 63;
  int wid = __builtin_amdgcn_readfirstlane(tid >> 6);
  int bx = (int)((blockIdx.x & 7) * 256 + (blockIdx.x >> 3));  // bijective XCD swizzle (2048=8*256)
  int bh = bx >> 7;
  int tile = (bx & 127) * 4;
  int h = bh & 3, b = bh >> 2;
  int sq0 = wid * 128;               // this wave's s-quarter base

  // EKT[bh][dc][q=wid][lane][8]: per lane 32B = {d0_lo,d0_hi,d1_lo,d1_hi,d2_lo,d2_hi,d3_lo,d3_hi}
  const float* ekb = EKT + (size_t)bh * (16 * 2048) + wid * 512 + lane * 8;
  const float* eqb = EQ + ((size_t)bh * TLEN + tile) * DH;   // uniform -> s_load
  const float* vap = va_g + h * DH;

  f2 acc2[4];
#pragma unroll
  for (int t = 0; t < 4; ++t) acc2[t] = s2(0.f);
  float vsum = 0.f;

  f2 a0_, a1_, a2_, a3_, b0_, b1_, b2_, b3_;

#define LOADP(E0, E1, E2, E3, dc_) do {                                     \
    const f2* _p = (const f2*)(ekb + (size_t)(dc_) * 2048);                 \
    E0 = _p[0]; E1 = _p[1]; E2 = _p[2]; E3 = _p[3];                         \
  } while (0)

  // packed quad-combined rcp: both s-slots in one f2 stream; 14 pk-VALU + 2 rcp
#define SC4P(E0, E1, E2, E3, qv, av, aref) do {                             \
    f2 A0 = f2fma(s2(qv.x), E0, s2(1.f));                                   \
    f2 A1 = f2fma(s2(qv.y), E1, s2(1.f));                                   \
    f2 A2 = f2fma(s2(qv.z), E2, s2(1.f));                                   \
    f2 A3 = f2fma(s2(qv.w), E3, s2(1.f));                                   \
    f2 n01 = f2fma(s2(av.x), A1, s2(av.y) * A0);                            \
    f2 n23 = f2fma(s2(av.z), A3, s2(av.w) * A2);                            \
    f2 P01 = A0 * A1, P23 = A2 * A3;                                        \
    f2 Nm = f2fma(n01, P23, n23 * P01);                                     \
    f2 PP = P01 * P23;                                                      \
    f2 R; R.x = rcp_fast(PP.x); R.y = rcp_fast(PP.y);                       \
    aref = f2fma(Nm, R, aref);                                              \
  } while (0)

#define DCBODYP(C0, C1, C2, C3, N0, N1, N2, N3, dc_) do {                   \
    float4 av = *(const float4*)(vap + (dc_) * 4);                          \
    float4 q0 = *(const float4*)(eqb + 0 * DH + (dc_) * 4);                 \
    float4 q1 = *(const float4*)(eqb + 1 * DH + (dc_) * 4);                 \
    float4 q2 = *(const float4*)(eqb + 2 * DH + (dc_) * 4);                 \
    float4 q3 = *(const float4*)(eqb + 3 * DH + (dc_) * 4);                 \
    vsum += (av.x + av.y) + (av.z + av.w);                                  \
    if ((dc_) < 15) LOADP(N0, N1, N2, N3, (dc_) + 1);                       \
    __builtin_amdgcn_sched_barrier(0);                                      \
    SC4P(C0, C1, C2, C3, q0, av, acc2[0]);                                  \
    SC4P(C0, C1, C2, C3, q1, av, acc2[1]);                                  \
    SC4P(C0, C1, C2, C3, q2, av, acc2[2]);                                  \
    SC4P(C0, C1, C2, C3, q3, av, acc2[3]);                                  \
  } while (0)

  LOADP(a0_, a1_, a2_, a3_, 0);
#pragma unroll 1
  for (int dc2 = 0; dc2 < 8; ++dc2) {
    DCBODYP(a0_, a1_, a2_, a3_, b0_, b1_, b2_, b3_, 2 * dc2);
    DCBODYP(b0_, b1_, b2_, b3_, a0_, a1_, a2_, a3_, 2 * dc2 + 1);
  }

  // ---- softmax, no max-subtraction (|score| <= 0.125*sum|va| ~ 7, exp bounded) ----
  size_t bht = (size_t)bh * TLEN + tile;
  float e0[4], e1[4];
#pragma unroll
  for (int t = 0; t < 4; ++t) {
    float x0 = __expf(fmaf(acc2[t].x, -0.25f, vsum * 0.125f));
    float x1 = __expf(fmaf(acc2[t].y, -0.25f, vsum * 0.125f));
    e0[t] = x0; e1[t] = x1;
    float es = x0 + x1;
#pragma unroll
    for (int off = 32; off; off >>= 1) es += __shfl_xor(es, off);
    if (lane == 0) sred[t][wid] = es;
  }
  __syncthreads();
#pragma unroll
  for (int t = 0; t < 4; ++t) {
    float es = (sred[t][0] + sred[t][1]) + (sred[t][2] + sred[t][3]);
    float inv = rcp_fast(es);
    float p0 = e0[t] * inv, p1 = e1[t] * inv;
    pw[t][sq0 + lane] = p0;                 // own-wave region: no barrier needed
    pw[t][sq0 + 64 + lane] = p1;
    float* arow = attn_out + (bht + t) * SLEN + sq0;
    arow[lane] = p0;                        // coalesced 256B stores
    arow[64 + lane] = p1;
  }

  // ---- PV over own s-quarter: lane = d; probs via LDS broadcast (own writes) ----
  const float2* vb = (const float2*)Vw + (size_t)bh * (256 * 64) + (size_t)(wid * 64) * 64 + lane;
  float f[4];
#pragma unroll
  for (int t = 0; t < 4; ++t) f[t] = 0.f;
#pragma unroll 2
  for (int i = 0; i < 32; ++i) {            // s-quads within quarter
    float2 v01 = vb[(size_t)i * 128];       // coalesced b64: s-pair, d=lane
    float2 v23 = vb[(size_t)i * 128 + 64];
    int sb = sq0 + i * 4;
#pragma unroll
    for (int t = 0; t < 4; ++t) {
      float4 pq = *(const float4*)&pw[t][sb];   // uniform addr -> LDS broadcast
      f[t] = fmaf(pq.x, v01.x, f[t]);
      f[t] = fmaf(pq.y, v01.y, f[t]);
      f[t] = fmaf(pq.z, v23.x, f[t]);
      f[t] = fmaf(pq.w, v23.y, f[t]);
    }
  }
#pragma unroll
  for (int t = 0; t < 4; ++t) fp[wid][t][lane] = f[t];
  __syncthreads();
  {
    int t = wid;                            // wave reduces 1 t-row
    float s = (fp[0][t][lane] + fp[1][t][lane]) + (fp[2][t][lane] + fp[3][t][lane]);
    attended[((size_t)(b * TLEN) + tile + t) * DM + h * DH + lane] = s;
  }
}

// ---- kernel C: out = attended @ w_o.T; block = 8 rows x 64 outs, grid 1024 ----
__global__ __launch_bounds__(256) void outproj_kernel(
    const float* __restrict__ att, const float* __restrict__ wot,
    float* __restrict__ out) {
  int tid = threadIdx.x;
  int lane = tid & 63;
  int wid = __builtin_amdgcn_readfirstlane(tid >> 6);
  int row0 = (blockIdx.x >> 2) * 8 + wid * 2;
  int o = (blockIdx.x & 3) * 64 + lane;
  const float* xb = att + (size_t)row0 * DM;       // wave-uniform -> s_load
  const float* wcol = wot + o;
  float a0 = 0.f, a1 = 0.f;
#pragma unroll 8
  for (int kk = 0; kk < DM; ++kk) {
    float w = wcol[(size_t)kk * DM];
    a0 = fmaf(xb[kk], w, a0);
    a1 = fmaf(xb[DM + kk], w, a1);
  }
  out[(size_t)(row0 + 0) * DM + o] = a0;
  out[(size_t)(row0 + 1) * DM + o] = a1;
}

extern "C" void kernel_launch(void* const* d_in, const int* in_sizes, int n_in,
                              void* d_out, int out_size, void* d_ws, size_t ws_size,
                              hipStream_t stream) {
  const float* query = (const float*)d_in[0];
  const float* key   = (const float*)d_in[1];
  const float* value = (const float*)d_in[2];
  const float* wq    = (const float*)d_in[3];
  const float* wk    = (const float*)d_in[4];
  const float* wv    = (const float*)d_in[5];
  const float* va    = (const float*)d_in[6];
  const float* wo    = (const float*)d_in[7];

  float* out  = (float*)d_out;                 // (B,T,DM)
  float* attn = out + (size_t)BT * DM;         // (B,H,T,S)

  const size_t SEG = (size_t)BT * DM;          // 524288 floats = 2MB
  float* EQ  = (float*)d_ws;                   // [bh][t][d]
  float* EKT = EQ + SEG;                       // [bh][dc16][q4][lane64][d4][2]
  float* Vw  = EKT + SEG;                      // [bh][s/2][d][2]
  float* att = Vw + SEG;                       // attended [b][t][h*64+d]

  bool big_ws = ws_size >= (4 * SEG + 4 * (size_t)DM * DM) * sizeof(float);

  if (big_ws) {
    // weights live past 8MB: all 4 transposes front-loaded, 4 kernels total
    float* WTq = att + SEG;
    float* WTk = WTq + (size_t)DM * DM;
    float* WTv = WTk + (size_t)DM * DM;
    float* WoT = WTv + (size_t)DM * DM;
    transposeN_kernel<<<dim3(16, 4), 256, 0, stream>>>(wq, wk, wv, wo, WTq, WTk, WTv, WoT);
    proj_kernel<<<dim3(512, 3), 256, 0, stream>>>(query, key, value, WTq, WTk, WTv, EQ, EKT, Vw);
    attn_kernel<<<dim3(2048), 256, 0, stream>>>(EQ, EKT, Vw, va, attn, att);
    outproj_kernel<<<dim3(1024), 256, 0, stream>>>(att, WoT, out);
  } else {
    // fallback: overlay weights in dead regions (5 kernels)
    float* WTq = att;                          // dead until attn writes att
    float* WTk = att + (size_t)DM * DM;
    float* WTv = att + 2 * (size_t)DM * DM;
    float* WoT = EQ;                           // EQ dead after attn
    transposeN_kernel<<<dim3(16, 3), 256, 0, stream>>>(wq, wk, wv, wv, WTq, WTk, WTv, WTv);
    proj_kernel<<<dim3(512, 3), 256, 0, stream>>>(query, key, value, WTq, WTk, WTv, EQ, EKT, Vw);
    attn_kernel<<<dim3(2048), 256, 0, stream>>>(EQ, EKT, Vw, va, attn, att);
    transposeN_kernel<<<dim3(16, 1), 256, 0, stream>>>(wo, wo, wo, wo, WoT, WoT, WoT, WoT);
    outproj_kernel<<<dim3(1024), 256, 0, stream>>>(att, WoT, out);
  }
}